// Round 16
// baseline (139.578 us; speedup 1.0000x reference)
//
#include <hip/hip_runtime.h>
#include <math.h>

#define D_IN   256
#define D_E    64
#define N_SUP  16384
#define NQ     256
#define KSEL   32
#define RTOLC  1e-5f
#define ATOLC  1e-5f
#define INV_T  10.0f    // 1/TEMPERATURE

#define CHUNK  512      // support rows per phase-A block
#define NCH    32       // support chunks
#define QG     16       // queries per phase-A block (2 per wave, 8 waves)
#define NQG    16       // query groups

typedef unsigned long long ull;

__device__ __forceinline__ float gelu_exact(float x) {
    return 0.5f * x * (1.0f + erff(x * 0.70710678118654752440f));
}

// ---------------------------------------------------------------------------
// Prep: transpose weights (W*T[k][f] = W[f][k]) so embed reads W as contiguous
// 16B-per-lane float4s over features. Tiny (24K elements).
__global__ __launch_bounds__(256) void prep_w(
    const float* __restrict__ W1, const float* __restrict__ W2,
    const float* __restrict__ W3,
    float* __restrict__ W1T, float* __restrict__ W2T, float* __restrict__ W3T)
{
    const int t = blockIdx.x * 256 + threadIdx.x;
    const int stride = gridDim.x * 256;
    for (int o = t; o < D_E * D_IN; o += stride) {
        int f = o >> 8, k = o & 255;
        W1T[k * D_E + f] = W1[o];
    }
    for (int o = t; o < D_E * D_E; o += stride) {
        int f = o >> 6, k = o & 63;
        W2T[k * D_E + f] = W2[o];
        W3T[k * D_E + f] = W3[o];
    }
}

// ---------------------------------------------------------------------------
// Embed: R13/R15 verbatim (measured 54 us, absmax 0). Kept unchanged this
// round to isolate the phase-A experiment.
__global__ __launch_bounds__(256) void embed_kernel(
    const float* __restrict__ sx, const float* __restrict__ x,
    const float* __restrict__ W1T, const float* __restrict__ b1,
    const float* __restrict__ W2T, const float* __restrict__ b2,
    const float* __restrict__ W3T, const float* __restrict__ b3,
    float* __restrict__ s_emb, float* __restrict__ s_norm,
    float* __restrict__ q_emb, float* __restrict__ q_norm)
{
    __shared__ float hx[32][68];      // hidden exchange, wave-private rows
    __shared__ float nsq[32][17];     // norm partials

    const int tid = threadIdx.x;
    const int rp  = tid >> 4;         // 0..15
    const int fg  = tid & 15;         // 0..15
    const bool isq = blockIdx.x >= (N_SUP / 32);
    const int rowb = (isq ? (int)blockIdx.x - N_SUP / 32 : (int)blockIdx.x) * 32;
    const float* src = (isq ? x : sx) + (size_t)rowb * D_IN;
    const float4* X4  = reinterpret_cast<const float4*>(src);    // [32][64]
    const float4* W14 = reinterpret_cast<const float4*>(W1T);    // [256][16]
    const float4* W24 = reinterpret_cast<const float4*>(W2T);    // [64][16]
    const float4* W34 = reinterpret_cast<const float4*>(W3T);    // [64][16]
    const int r0 = 2 * rp, r1 = 2 * rp + 1;

    #define FMA4(acc_, w_, xs_)                                                \
        acc_.x = fmaf(w_.x, xs_, acc_.x); acc_.y = fmaf(w_.y, xs_, acc_.y);    \
        acc_.z = fmaf(w_.z, xs_, acc_.z); acc_.w = fmaf(w_.w, xs_, acc_.w);

    // ---- layer 1: K=256, k ascending
    float4 acc0 = reinterpret_cast<const float4*>(b1)[fg];
    float4 acc1 = acc0;
    #pragma unroll 4
    for (int k4 = 0; k4 < 64; ++k4) {
        float4 xa = X4[r0 * 64 + k4];
        float4 xb = X4[r1 * 64 + k4];
        float4 wa = W14[(4 * k4 + 0) * 16 + fg];
        float4 wb = W14[(4 * k4 + 1) * 16 + fg];
        float4 wc = W14[(4 * k4 + 2) * 16 + fg];
        float4 wd = W14[(4 * k4 + 3) * 16 + fg];
        FMA4(acc0, wa, xa.x); FMA4(acc0, wb, xa.y);
        FMA4(acc0, wc, xa.z); FMA4(acc0, wd, xa.w);
        FMA4(acc1, wa, xb.x); FMA4(acc1, wb, xb.y);
        FMA4(acc1, wc, xb.z); FMA4(acc1, wd, xb.w);
    }
    *reinterpret_cast<float4*>(&hx[r0][fg * 4]) = make_float4(
        gelu_exact(acc0.x), gelu_exact(acc0.y), gelu_exact(acc0.z), gelu_exact(acc0.w));
    *reinterpret_cast<float4*>(&hx[r1][fg * 4]) = make_float4(
        gelu_exact(acc1.x), gelu_exact(acc1.y), gelu_exact(acc1.z), gelu_exact(acc1.w));
    // rows r0,r1 are produced & consumed by this wave only: lgkmcnt orders.

    // ---- layer 2: K=64
    float4 c0 = reinterpret_cast<const float4*>(b2)[fg];
    float4 c1 = c0;
    #pragma unroll 4
    for (int k4 = 0; k4 < 16; ++k4) {
        float4 xa = *reinterpret_cast<const float4*>(&hx[r0][k4 * 4]);
        float4 xb = *reinterpret_cast<const float4*>(&hx[r1][k4 * 4]);
        float4 wa = W24[(4 * k4 + 0) * 16 + fg];
        float4 wb = W24[(4 * k4 + 1) * 16 + fg];
        float4 wc = W24[(4 * k4 + 2) * 16 + fg];
        float4 wd = W24[(4 * k4 + 3) * 16 + fg];
        FMA4(c0, wa, xa.x); FMA4(c0, wb, xa.y);
        FMA4(c0, wc, xa.z); FMA4(c0, wd, xa.w);
        FMA4(c1, wa, xb.x); FMA4(c1, wb, xb.y);
        FMA4(c1, wc, xb.z); FMA4(c1, wd, xb.w);
    }
    *reinterpret_cast<float4*>(&hx[r0][fg * 4]) = make_float4(
        gelu_exact(c0.x), gelu_exact(c0.y), gelu_exact(c0.z), gelu_exact(c0.w));
    *reinterpret_cast<float4*>(&hx[r1][fg * 4]) = make_float4(
        gelu_exact(c1.x), gelu_exact(c1.y), gelu_exact(c1.z), gelu_exact(c1.w));

    // ---- layer 3: K=64, sigmoid + norm
    float4 d0 = reinterpret_cast<const float4*>(b3)[fg];
    float4 d1 = d0;
    #pragma unroll 4
    for (int k4 = 0; k4 < 16; ++k4) {
        float4 xa = *reinterpret_cast<const float4*>(&hx[r0][k4 * 4]);
        float4 xb = *reinterpret_cast<const float4*>(&hx[r1][k4 * 4]);
        float4 wa = W34[(4 * k4 + 0) * 16 + fg];
        float4 wb = W34[(4 * k4 + 1) * 16 + fg];
        float4 wc = W34[(4 * k4 + 2) * 16 + fg];
        float4 wd = W34[(4 * k4 + 3) * 16 + fg];
        FMA4(d0, wa, xa.x); FMA4(d0, wb, xa.y);
        FMA4(d0, wc, xa.z); FMA4(d0, wd, xa.w);
        FMA4(d1, wa, xb.x); FMA4(d1, wb, xb.y);
        FMA4(d1, wc, xb.z); FMA4(d1, wd, xb.w);
    }
    #undef FMA4

    float* E   = isq ? q_emb  : s_emb;
    float* Nrm = isq ? q_norm : s_norm;
    {
        float e0 = 1.0f / (1.0f + expf(-d0.x));
        float e1 = 1.0f / (1.0f + expf(-d0.y));
        float e2 = 1.0f / (1.0f + expf(-d0.z));
        float e3 = 1.0f / (1.0f + expf(-d0.w));
        *reinterpret_cast<float4*>(E + (size_t)(rowb + r0) * D_E + fg * 4) =
            make_float4(e0, e1, e2, e3);
        nsq[r0][fg] = fmaf(e0, e0, fmaf(e1, e1, fmaf(e2, e2, e3 * e3)));
    }
    {
        float e0 = 1.0f / (1.0f + expf(-d1.x));
        float e1 = 1.0f / (1.0f + expf(-d1.y));
        float e2 = 1.0f / (1.0f + expf(-d1.z));
        float e3 = 1.0f / (1.0f + expf(-d1.w));
        *reinterpret_cast<float4*>(E + (size_t)(rowb + r1) * D_E + fg * 4) =
            make_float4(e0, e1, e2, e3);
        nsq[r1][fg] = fmaf(e0, e0, fmaf(e1, e1, fmaf(e2, e2, e3 * e3)));
    }
    __syncthreads();
    if (tid < 32) {
        float s = 0.0f;
        #pragma unroll
        for (int g = 0; g < 16; ++g) s += nsq[tid][g];   // fixed order: exact bits
        Nrm[rowb + tid] = s;
    }
}

// ---------------------------------------------------------------------------
// Phase A EXPERIMENT: NO LDS tile, NO barriers anywhere. Each lane reads its
// own support row directly from L2 (64 lanes x 16B = coalesced 1KB/instr;
// s_emb is L2-resident; ~0.5 GB total L2 traffic << 34.5 TB/s). This removes
// the per-stage __syncthreads whose implicit vmcnt/lgkm drain is the prime
// suspect for the persistent ~3x latency overhead of every tiled variant.
// FMA chain per row is c-ascending = bit-identical d2 to R15 -> selection
// (R15 verbatim from the xor-transpose on) -> absmax 0.
__global__ __launch_bounds__(512) void knn_phaseA(
    const float* __restrict__ s_emb, const float* __restrict__ s_norm,
    const float* __restrict__ q_emb, const float* __restrict__ q_norm,
    const float* __restrict__ labels, ull* __restrict__ cand)
{
    __shared__ ull win_l[QG][KSEL];             // 4 KB; same-wave use only

    const int tid  = threadIdx.x;
    const int lane = tid & 63;
    const int wid  = tid >> 6;                  // 0..7
    const int qg   = blockIdx.x >> 5;
    const int sc   = blockIdx.x & 31;
    const int qiu  = __builtin_amdgcn_readfirstlane(qg * QG + 2 * wid);
    const float* q0 = q_emb + (size_t)qiu * D_E;     // uniform -> s_load
    const float* q1 = q0 + D_E;
    const float  qn0 = q_norm[qiu];
    const float  qn1 = q_norm[qiu + 1];

    float d2a[8], d2b[8];
    #pragma unroll
    for (int s = 0; s < 8; ++s) {               // FULL unroll: static d2 indices
        const int grow = sc * CHUNK + s * 64 + lane;
        const float* rp = s_emb + (size_t)grow * D_E;
        float a0 = 0.0f, a1 = 0.0f;
        #pragma unroll
        for (int c = 0; c < 16; ++c) {
            float4 sv = *reinterpret_cast<const float4*>(rp + c * 4);
            a0 = fmaf(q0[c * 4 + 0], sv.x, a0);
            a0 = fmaf(q0[c * 4 + 1], sv.y, a0);
            a0 = fmaf(q0[c * 4 + 2], sv.z, a0);
            a0 = fmaf(q0[c * 4 + 3], sv.w, a0);
            a1 = fmaf(q1[c * 4 + 0], sv.x, a1);
            a1 = fmaf(q1[c * 4 + 1], sv.y, a1);
            a1 = fmaf(q1[c * 4 + 2], sv.z, a1);
            a1 = fmaf(q1[c * 4 + 3], sv.w, a1);
        }
        const float sn = s_norm[grow];
        float d20 = fmaxf(qn0 + sn - 2.0f * a0, 0.0f);
        float d21 = fmaxf(qn1 + sn - 2.0f * a1, 0.0f);
        if (d20 < 1e-3f) {
            // possible isclose duplicate (true mask needs d2 <= 2.6e-8; fp32
            // error <= ~1e-5 -> 100x margin, ~never taken); all cold reads.
            bool close = true;
            for (int k = 0; k < D_E; ++k) {
                float svk = rp[k];
                close = close && (fabsf(q0[k] - svk) <= (ATOLC + RTOLC * fabsf(svk)));
            }
            if (close) d20 = INFINITY;
        }
        if (d21 < 1e-3f) {
            bool close = true;
            for (int k = 0; k < D_E; ++k) {
                float svk = rp[k];
                close = close && (fabsf(q1[k] - svk) <= (ATOLC + RTOLC * fabsf(svk)));
            }
            if (close) d21 = INFINITY;
        }
        d2a[s] = d20;
        d2b[s] = d21;
    }

    // ---- xor-32 transpose: half h owns query (2*wid+h); 16 keys/lane
    const int h  = lane >> 5;
    const unsigned l5 = lane & 31;
    ull sk[16];
    #pragma unroll
    for (int j = 0; j < 8; ++j) {
        float ta  = __shfl_xor(d2a[j], 32);
        float tbx = __shfl_xor(d2b[j], 32);
        float vlo = h ? tbx : d2a[j];           // row j*64 + l5
        float vhi = h ? d2b[j] : ta;            // row j*64 + l5 + 32
        unsigned rlo = (unsigned)(j * 64) + l5;
        sk[j]     = ((ull)__float_as_uint(vlo) << 9) | rlo;
        sk[j + 8] = ((ull)__float_as_uint(vhi) << 9) | (rlo + 32);
    }

    // bitonic sort 16 ascending (static indices)
    #pragma unroll
    for (int k = 2; k <= 16; k <<= 1) {
        #pragma unroll
        for (int j = k >> 1; j > 0; j >>= 1) {
            #pragma unroll
            for (int i = 0; i < 16; ++i) {
                int ixj = i ^ j;
                if (ixj > i) {
                    ull a_ = sk[i], b_ = sk[ixj];
                    bool up = (i & k) == 0;
                    bool c_ = up ? (b_ < a_) : (a_ < b_);
                    sk[i] = c_ ? b_ : a_; sk[ixj] = c_ ? a_ : b_;
                }
            }
        }
    }

    // ---- 32 rounds, both halves in parallel (5-step within-half chains)
    ull lkey = sk[0];
    for (int it = 0; it < KSEL; ++it) {
        unsigned lv = (unsigned)(lkey >> 9);
        unsigned m = lv;
        #pragma unroll
        for (int off = 1; off < 32; off <<= 1) {
            unsigned o = __shfl_xor(m, off);
            m = o < m ? o : m;
        }
        ull tb = __ballot(lv == m);
        bool cond;
        if (__popcll(tb) != 2) {                // rare: d2 tie -> min row wins
            unsigned rr = (lv == m) ? (unsigned)(lkey & 511u) : 0xffffffffu;
            unsigned rm = rr;
            #pragma unroll
            for (int off = 1; off < 32; off <<= 1) {
                unsigned o = __shfl_xor(rm, off);
                rm = o < rm ? o : rm;
            }
            cond = (lv == m) && ((unsigned)(lkey & 511u) == rm);
        } else {
            cond = (lv == m);                   // exactly one lane per half
        }
        if (cond) {
            win_l[2 * wid + h][it] = lkey;
            #pragma unroll
            for (int j = 0; j < 15; ++j) sk[j] = sk[j + 1];
            sk[15] = ~0ull;
            lkey = sk[0];
        }
    }

    // ---- parallel label fetch + emit (sorted by (d2, idx)); same-wave LDS
    // ordering (write-before-read in issue order) -> no barrier needed.
    {
        const int e = (int)l5;
        ull m = win_l[2 * wid + h][e];
        unsigned gidx = (unsigned)(sc * CHUNK) + (unsigned)(m & 511u);
        float lab = labels[gidx];
        ull* dst = cand + ((size_t)(qg * QG + 2 * wid + h) * NCH + sc) * KSEL;
        dst[e] = ((ull)(unsigned)(m >> 9) << 32) | (ull)__float_as_uint(lab);
    }
}

// ---------------------------------------------------------------------------
// Phase B: UNCHANGED (absmax 0). Wave per query; lanes 0..31 merge the 32
// sorted chunk lists; labels ride in the candidate payload.
__global__ __launch_bounds__(256) void knn_phaseB(
    const ull* __restrict__ cand, float* __restrict__ out)
{
    const int lane = threadIdx.x & 63;
    const int wid  = threadIdx.x >> 6;
    const int q    = blockIdx.x * 4 + wid;

    const bool act = lane < NCH;
    const ull* lst = cand + ((size_t)q * NCH + (lane & 31)) * KSEL;
    int ptr = 0;
    ull cur = act ? lst[0] : ~0ull;

    float d0 = 0.0f, sw = 0.0f, sl = 0.0f;
    for (int it = 0; it < KSEL; ++it) {
        unsigned mv = (unsigned)(cur >> 32);
        unsigned ml = (unsigned)cur;
        #pragma unroll
        for (int off = 1; off < 32; off <<= 1) {
            unsigned ov = __shfl_xor(mv, off);
            unsigned ol = __shfl_xor(ml, off);
            bool take = (ov < mv) || (ov == mv && (lane & off));
            mv = take ? ov : mv;
            ml = take ? ol : ml;
        }
        ull bl = __ballot(act && (unsigned)(cur >> 32) == mv);
        int wl = (int)(__ffsll((long long)bl) - 1);
        if (lane == wl) {
            ++ptr;
            cur = (ptr < KSEL) ? lst[ptr] : ~0ull;
        }
        if (lane == 0) {
            float d = sqrtf(__uint_as_float(mv));
            if (it == 0) d0 = d;
            float w = expf((d0 - d) * INV_T);
            sw += w;
            sl += w * __uint_as_float(ml);
        }
    }
    if (lane == 0) out[q] = sl / sw;
}

// ---------------------------------------------------------------------------
extern "C" void kernel_launch(void* const* d_in, const int* in_sizes, int n_in,
                              void* d_out, int out_size, void* d_ws, size_t ws_size,
                              hipStream_t stream) {
    const float* x      = (const float*)d_in[0];   // [256,256]
    const float* sx     = (const float*)d_in[1];   // [16384,256]
    const float* labels = (const float*)d_in[2];   // [16384,1]
    const float* W1     = (const float*)d_in[3];   // [64,256]
    const float* b1     = (const float*)d_in[4];
    const float* W2     = (const float*)d_in[5];   // [64,64]
    const float* b2     = (const float*)d_in[6];
    const float* W3     = (const float*)d_in[7];   // [64,64]
    const float* b3     = (const float*)d_in[8];
    float* out = (float*)d_out;

    float* ws     = (float*)d_ws;
    float* s_emb  = ws;                              // 16384*64
    float* s_norm = s_emb + (size_t)N_SUP * D_E;     // 16384
    float* q_emb  = s_norm + N_SUP;                  // 256*64
    float* q_norm = q_emb + (size_t)NQ * D_E;        // 256
    ull*   cand   = (ull*)(q_norm + NQ);             // 256*32*32 ull = 2 MB
    float* W1T    = (float*)(cand + (size_t)NQ * NCH * KSEL);   // 256*64
    float* W2T    = W1T + D_IN * D_E;                // 64*64
    float* W3T    = W2T + D_E * D_E;                 // 64*64

    prep_w<<<32, 256, 0, stream>>>(W1, W2, W3, W1T, W2T, W3T);
    embed_kernel<<<(N_SUP + NQ) / 32, 256, 0, stream>>>(
        sx, x, W1T, b1, W2T, b2, W3T, b3, s_emb, s_norm, q_emb, q_norm);
    knn_phaseA<<<NQG * NCH, 512, 0, stream>>>(s_emb, s_norm, q_emb, q_norm,
                                              labels, cand);
    knn_phaseB<<<NQ / 4, 256, 0, stream>>>(cand, out);
}

// Round 17
// 92.110 us; speedup vs baseline: 1.5153x; 1.5153x over previous
//
#include <hip/hip_runtime.h>
#include <math.h>

#define D_IN   256
#define D_E    64
#define N_SUP  16384
#define NQ     256
#define KSEL   32
#define RTOLC  1e-5f
#define ATOLC  1e-5f
#define INV_T  10.0f    // 1/TEMPERATURE

#define CHUNK  512      // support rows per phase-A block
#define NCH    32       // support chunks
#define QG     16       // queries per phase-A block (2 per wave, 8 waves)
#define NQG    16       // query groups

typedef unsigned long long ull;

__device__ __forceinline__ float gelu_exact(float x) {
    return 0.5f * x * (1.0f + erff(x * 0.70710678118654752440f));
}

// ---------------------------------------------------------------------------
// Embed: R11's kernel verbatim (best measured embed: ~45 us, absmax 0).
// 260 blocks x 256 threads. Block = 64 rows. Thread = 4 rows x 4 feats
// register tile: per k, 1 ds_read_b128 (x) + 1 ds_read_b128 (w) = 16 FMA /
// 2 LDS instr. Stages raw W (no prep kernel). FMA chain k-ascending.
__global__ __launch_bounds__(256, 2) void embed_kernel(
    const float* __restrict__ sx, const float* __restrict__ x,
    const float* __restrict__ W1, const float* __restrict__ b1,
    const float* __restrict__ W2, const float* __restrict__ b2,
    const float* __restrict__ W3, const float* __restrict__ b3,
    float* __restrict__ s_emb, float* __restrict__ s_norm,
    float* __restrict__ q_emb, float* __restrict__ q_norm)
{
    __shared__ float xc[2][64][68];   // x chunk [k][row]; xc[0] later hA, xc[1] hB
    __shared__ float wc[2][64][68];   // W chunk [k][f];   wc[0] later W2T, wc[1] W3T
    __shared__ float nsq[64][17];

    const int tid = threadIdx.x;
    const int rg  = tid >> 4;         // row group (4 rows)
    const int fg  = tid & 15;         // feature group (4 feats)
    const bool isq = blockIdx.x >= (N_SUP / 64);
    const int rowbase = isq ? (int)(blockIdx.x - N_SUP / 64) * 64
                            : (int)blockIdx.x * 64;
    const float* src = (isq ? x : sx) + (size_t)rowbase * D_IN;

    #define STAGE_X(kc_, b_)                                                   \
        {                                                                      \
            _Pragma("unroll")                                                  \
            for (int i_ = 0; i_ < 4; ++i_) {                                   \
                int g_ = i_ * 256 + tid;                                       \
                int row_ = g_ >> 4, c4_ = g_ & 15;                             \
                float4 v_ = *reinterpret_cast<const float4*>(                  \
                    src + (size_t)row_ * D_IN + (kc_) * 64 + c4_ * 4);         \
                xc[b_][c4_ * 4 + 0][row_] = v_.x;                              \
                xc[b_][c4_ * 4 + 1][row_] = v_.y;                              \
                xc[b_][c4_ * 4 + 2][row_] = v_.z;                              \
                xc[b_][c4_ * 4 + 3][row_] = v_.w;                              \
            }                                                                  \
        }
    #define STAGE_W1(kc_, b_)                                                  \
        {                                                                      \
            _Pragma("unroll")                                                  \
            for (int i_ = 0; i_ < 4; ++i_) {                                   \
                int g_ = i_ * 256 + tid;                                       \
                int f_ = g_ >> 4, c4_ = g_ & 15;                               \
                float4 w_ = *reinterpret_cast<const float4*>(                  \
                    W1 + (size_t)f_ * D_IN + (kc_) * 64 + c4_ * 4);            \
                wc[b_][c4_ * 4 + 0][f_] = w_.x;                                \
                wc[b_][c4_ * 4 + 1][f_] = w_.y;                                \
                wc[b_][c4_ * 4 + 2][f_] = w_.z;                                \
                wc[b_][c4_ * 4 + 3][f_] = w_.w;                                \
            }                                                                  \
        }
    #define STAGE_WSQ(Wp_, b_)                                                 \
        {                                                                      \
            _Pragma("unroll")                                                  \
            for (int i_ = 0; i_ < 4; ++i_) {                                   \
                int g_ = i_ * 256 + tid;                                       \
                int f_ = g_ >> 4, c4_ = g_ & 15;                               \
                float4 w_ = *reinterpret_cast<const float4*>(                  \
                    (Wp_) + (size_t)f_ * D_E + c4_ * 4);                       \
                wc[b_][c4_ * 4 + 0][f_] = w_.x;                                \
                wc[b_][c4_ * 4 + 1][f_] = w_.y;                                \
                wc[b_][c4_ * 4 + 2][f_] = w_.z;                                \
                wc[b_][c4_ * 4 + 3][f_] = w_.w;                                \
            }                                                                  \
        }
    #define GEMM64(XB_, WB_, ACC_)                                             \
        {                                                                      \
            _Pragma("unroll 8")                                                \
            for (int k_ = 0; k_ < 64; ++k_) {                                  \
                float4 xv_ = *reinterpret_cast<const float4*>(&XB_[k_][rg * 4]); \
                float4 wv_ = *reinterpret_cast<const float4*>(&WB_[k_][fg * 4]); \
                ACC_[0][0] = fmaf(wv_.x, xv_.x, ACC_[0][0]);                   \
                ACC_[0][1] = fmaf(wv_.y, xv_.x, ACC_[0][1]);                   \
                ACC_[0][2] = fmaf(wv_.z, xv_.x, ACC_[0][2]);                   \
                ACC_[0][3] = fmaf(wv_.w, xv_.x, ACC_[0][3]);                   \
                ACC_[1][0] = fmaf(wv_.x, xv_.y, ACC_[1][0]);                   \
                ACC_[1][1] = fmaf(wv_.y, xv_.y, ACC_[1][1]);                   \
                ACC_[1][2] = fmaf(wv_.z, xv_.y, ACC_[1][2]);                   \
                ACC_[1][3] = fmaf(wv_.w, xv_.y, ACC_[1][3]);                   \
                ACC_[2][0] = fmaf(wv_.x, xv_.z, ACC_[2][0]);                   \
                ACC_[2][1] = fmaf(wv_.y, xv_.z, ACC_[2][1]);                   \
                ACC_[2][2] = fmaf(wv_.z, xv_.z, ACC_[2][2]);                   \
                ACC_[2][3] = fmaf(wv_.w, xv_.z, ACC_[2][3]);                   \
                ACC_[3][0] = fmaf(wv_.x, xv_.w, ACC_[3][0]);                   \
                ACC_[3][1] = fmaf(wv_.y, xv_.w, ACC_[3][1]);                   \
                ACC_[3][2] = fmaf(wv_.z, xv_.w, ACC_[3][2]);                   \
                ACC_[3][3] = fmaf(wv_.w, xv_.w, ACC_[3][3]);                   \
            }                                                                  \
        }

    // ---- layer 1: K=256 in 4 chunks, double-buffered
    float4 bv1 = *reinterpret_cast<const float4*>(b1 + fg * 4);
    float acc[4][4];
    #pragma unroll
    for (int j = 0; j < 4; ++j) {
        acc[j][0] = bv1.x; acc[j][1] = bv1.y; acc[j][2] = bv1.z; acc[j][3] = bv1.w;
    }
    STAGE_X(0, 0); STAGE_W1(0, 0);
    __syncthreads();
    #pragma unroll
    for (int kc = 0; kc < 4; ++kc) {
        const int b = kc & 1;
        if (kc < 3) { STAGE_X(kc + 1, b ^ 1); STAGE_W1(kc + 1, b ^ 1); }
        GEMM64(xc[b], wc[b], acc);
        __syncthreads();
    }

    // hA (gelu) -> xc[0] transposed [f][row]; stage W2 -> wc[0], W3 -> wc[1]
    #pragma unroll
    for (int j = 0; j < 4; ++j)
        #pragma unroll
        for (int i = 0; i < 4; ++i)
            xc[0][fg * 4 + i][rg * 4 + j] = gelu_exact(acc[j][i]);
    STAGE_WSQ(W2, 0);
    STAGE_WSQ(W3, 1);
    __syncthreads();

    // ---- layer 2: hA (xc[0]) x W2T (wc[0]) -> hB (xc[1])
    float4 bv2 = *reinterpret_cast<const float4*>(b2 + fg * 4);
    float a2[4][4];
    #pragma unroll
    for (int j = 0; j < 4; ++j) {
        a2[j][0] = bv2.x; a2[j][1] = bv2.y; a2[j][2] = bv2.z; a2[j][3] = bv2.w;
    }
    GEMM64(xc[0], wc[0], a2);
    __syncthreads();
    #pragma unroll
    for (int j = 0; j < 4; ++j)
        #pragma unroll
        for (int i = 0; i < 4; ++i)
            xc[1][fg * 4 + i][rg * 4 + j] = gelu_exact(a2[j][i]);
    __syncthreads();

    // ---- layer 3: hB (xc[1]) x W3T (wc[1]) -> sigmoid + norm
    float4 bv3 = *reinterpret_cast<const float4*>(b3 + fg * 4);
    float a3[4][4];
    #pragma unroll
    for (int j = 0; j < 4; ++j) {
        a3[j][0] = bv3.x; a3[j][1] = bv3.y; a3[j][2] = bv3.z; a3[j][3] = bv3.w;
    }
    GEMM64(xc[1], wc[1], a3);

    float* E   = isq ? q_emb  : s_emb;
    float* Nrm = isq ? q_norm : s_norm;
    #pragma unroll
    for (int j = 0; j < 4; ++j) {
        float e0 = 1.0f / (1.0f + expf(-a3[j][0]));
        float e1 = 1.0f / (1.0f + expf(-a3[j][1]));
        float e2 = 1.0f / (1.0f + expf(-a3[j][2]));
        float e3 = 1.0f / (1.0f + expf(-a3[j][3]));
        *reinterpret_cast<float4*>(E + (size_t)(rowbase + rg * 4 + j) * D_E + fg * 4)
            = make_float4(e0, e1, e2, e3);
        a3[j][0] = fmaf(e0, e0, fmaf(e1, e1, fmaf(e2, e2, e3 * e3)));
    }
    __syncthreads();                  // xc/wc reads done
    #pragma unroll
    for (int j = 0; j < 4; ++j) nsq[rg * 4 + j][fg] = a3[j][0];
    __syncthreads();
    if (tid < 64) {
        float s = 0.0f;
        #pragma unroll
        for (int g = 0; g < 16; ++g) s += nsq[tid][g];
        Nrm[rowbase + tid] = s;
    }
    #undef STAGE_X
    #undef STAGE_W1
    #undef STAGE_WSQ
    #undef GEMM64
}

// ---------------------------------------------------------------------------
// Phase A: R15's tiled kernel verbatim (best measured: ~49 us, absmax 0).
// grid 512 (qg = b>>5, sc = b&31), 512 threads, wave = 2 queries via SGPR
// q-pointers; xor-32 transpose -> both queries' top-32 run in parallel halves.
__global__ __launch_bounds__(512, 2) void knn_phaseA(
    const float* __restrict__ s_emb, const float* __restrict__ s_norm,
    const float* __restrict__ q_emb, const float* __restrict__ q_norm,
    const float* __restrict__ labels, ull* __restrict__ cand)
{
    __shared__ float tile[2][64 * 68];          // 34.8 KB
    __shared__ ull   win_l[QG][KSEL];           // 4 KB

    const int tid  = threadIdx.x;
    const int lane = tid & 63;
    const int wid  = tid >> 6;                  // 0..7
    const int qg   = blockIdx.x >> 5;
    const int sc   = blockIdx.x & 31;
    const int qiu  = __builtin_amdgcn_readfirstlane(qg * QG + 2 * wid);
    const float* q0 = q_emb + (size_t)qiu * D_E;     // uniform -> s_load
    const float* q1 = q0 + D_E;
    const float  qn0 = q_norm[qiu];
    const float  qn1 = q_norm[qiu + 1];

    #pragma unroll
    for (int i = 0; i < 2; ++i) {               // stage 0
        int g = i * 512 + tid;
        int row = g >> 4, c4 = g & 15;
        float4 v = *reinterpret_cast<const float4*>(
            s_emb + (size_t)(sc * CHUNK + row) * D_E + c4 * 4);
        *reinterpret_cast<float4*>(&tile[0][row * 68 + c4 * 4]) = v;
    }
    __syncthreads();

    float d2a[8], d2b[8];
    #pragma unroll
    for (int s = 0; s < 8; ++s) {               // FULL unroll: static d2 indices
        const int b = s & 1;
        float4 p0, p1;
        if (s < 7) {                            // issue prefetch loads early
            p0 = *reinterpret_cast<const float4*>(
                s_emb + (size_t)(sc * CHUNK + (s + 1) * 64 + (tid >> 4)) * D_E + (tid & 15) * 4);
            p1 = *reinterpret_cast<const float4*>(
                s_emb + (size_t)(sc * CHUNK + (s + 1) * 64 + ((512 + tid) >> 4)) * D_E + (tid & 15) * 4);
        }
        const float* tr = &tile[b][lane * 68];
        float a0 = 0.0f, a1 = 0.0f;
        #pragma unroll
        for (int c = 0; c < 16; ++c) {
            float4 sv = *reinterpret_cast<const float4*>(tr + c * 4);
            a0 = fmaf(q0[c * 4 + 0], sv.x, a0);
            a0 = fmaf(q0[c * 4 + 1], sv.y, a0);
            a0 = fmaf(q0[c * 4 + 2], sv.z, a0);
            a0 = fmaf(q0[c * 4 + 3], sv.w, a0);
            a1 = fmaf(q1[c * 4 + 0], sv.x, a1);
            a1 = fmaf(q1[c * 4 + 1], sv.y, a1);
            a1 = fmaf(q1[c * 4 + 2], sv.z, a1);
            a1 = fmaf(q1[c * 4 + 3], sv.w, a1);
        }
        const int grow = sc * CHUNK + s * 64 + lane;
        const float sn = s_norm[grow];
        float d20 = fmaxf(qn0 + sn - 2.0f * a0, 0.0f);
        float d21 = fmaxf(qn1 + sn - 2.0f * a1, 0.0f);
        if (d20 < 1e-3f) {
            // possible isclose duplicate (true mask needs d2 <= 2.6e-8; fp32
            // error <= ~1e-5 -> 100x margin, ~never taken); q via s_load.
            bool close = true;
            for (int k = 0; k < D_E; ++k) {
                float svk = tr[k];
                close = close && (fabsf(q0[k] - svk) <= (ATOLC + RTOLC * fabsf(svk)));
            }
            if (close) d20 = INFINITY;
        }
        if (d21 < 1e-3f) {
            bool close = true;
            for (int k = 0; k < D_E; ++k) {
                float svk = tr[k];
                close = close && (fabsf(q1[k] - svk) <= (ATOLC + RTOLC * fabsf(svk)));
            }
            if (close) d21 = INFINITY;
        }
        d2a[s] = d20;
        d2b[s] = d21;
        if (s < 7) {                            // write prefetch after compute
            *reinterpret_cast<float4*>(&tile[b ^ 1][(tid >> 4) * 68 + (tid & 15) * 4]) = p0;
            *reinterpret_cast<float4*>(&tile[b ^ 1][((512 + tid) >> 4) * 68 + (tid & 15) * 4]) = p1;
        }
        __syncthreads();
    }

    // ---- xor-32 transpose: half h owns query (2*wid+h); 16 keys/lane
    const int h  = lane >> 5;
    const unsigned l5 = lane & 31;
    ull sk[16];
    #pragma unroll
    for (int j = 0; j < 8; ++j) {
        float ta  = __shfl_xor(d2a[j], 32);
        float tbx = __shfl_xor(d2b[j], 32);
        float vlo = h ? tbx : d2a[j];           // row j*64 + l5
        float vhi = h ? d2b[j] : ta;            // row j*64 + l5 + 32
        unsigned rlo = (unsigned)(j * 64) + l5;
        sk[j]     = ((ull)__float_as_uint(vlo) << 9) | rlo;
        sk[j + 8] = ((ull)__float_as_uint(vhi) << 9) | (rlo + 32);
    }

    // bitonic sort 16 ascending (static indices)
    #pragma unroll
    for (int k = 2; k <= 16; k <<= 1) {
        #pragma unroll
        for (int j = k >> 1; j > 0; j >>= 1) {
            #pragma unroll
            for (int i = 0; i < 16; ++i) {
                int ixj = i ^ j;
                if (ixj > i) {
                    ull a_ = sk[i], b_ = sk[ixj];
                    bool up = (i & k) == 0;
                    bool c_ = up ? (b_ < a_) : (a_ < b_);
                    sk[i] = c_ ? b_ : a_; sk[ixj] = c_ ? a_ : b_;
                }
            }
        }
    }

    // ---- 32 rounds, both halves in parallel (5-step within-half chains)
    ull lkey = sk[0];
    for (int it = 0; it < KSEL; ++it) {
        unsigned lv = (unsigned)(lkey >> 9);
        unsigned m = lv;
        #pragma unroll
        for (int off = 1; off < 32; off <<= 1) {
            unsigned o = __shfl_xor(m, off);
            m = o < m ? o : m;
        }
        ull tb = __ballot(lv == m);
        bool cond;
        if (__popcll(tb) != 2) {                // rare: d2 tie -> min row wins
            unsigned rr = (lv == m) ? (unsigned)(lkey & 511u) : 0xffffffffu;
            unsigned rm = rr;
            #pragma unroll
            for (int off = 1; off < 32; off <<= 1) {
                unsigned o = __shfl_xor(rm, off);
                rm = o < rm ? o : rm;
            }
            cond = (lv == m) && ((unsigned)(lkey & 511u) == rm);
        } else {
            cond = (lv == m);                   // exactly one lane per half
        }
        if (cond) {
            win_l[2 * wid + h][it] = lkey;
            #pragma unroll
            for (int j = 0; j < 15; ++j) sk[j] = sk[j + 1];
            sk[15] = ~0ull;
            lkey = sk[0];
        }
    }

    // ---- parallel label fetch + emit (sorted by (d2, idx))
    {
        const int e = (int)l5;
        ull m = win_l[2 * wid + h][e];
        unsigned gidx = (unsigned)(sc * CHUNK) + (unsigned)(m & 511u);
        float lab = labels[gidx];
        ull* dst = cand + ((size_t)(qg * QG + 2 * wid + h) * NCH + sc) * KSEL;
        dst[e] = ((ull)(unsigned)(m >> 9) << 32) | (ull)__float_as_uint(lab);
    }
}

// ---------------------------------------------------------------------------
// Phase B: UNCHANGED (absmax 0). Wave per query; lanes 0..31 merge the 32
// sorted chunk lists; labels ride in the candidate payload.
__global__ __launch_bounds__(256) void knn_phaseB(
    const ull* __restrict__ cand, float* __restrict__ out)
{
    const int lane = threadIdx.x & 63;
    const int wid  = threadIdx.x >> 6;
    const int q    = blockIdx.x * 4 + wid;

    const bool act = lane < NCH;
    const ull* lst = cand + ((size_t)q * NCH + (lane & 31)) * KSEL;
    int ptr = 0;
    ull cur = act ? lst[0] : ~0ull;

    float d0 = 0.0f, sw = 0.0f, sl = 0.0f;
    for (int it = 0; it < KSEL; ++it) {
        unsigned mv = (unsigned)(cur >> 32);
        unsigned ml = (unsigned)cur;
        #pragma unroll
        for (int off = 1; off < 32; off <<= 1) {
            unsigned ov = __shfl_xor(mv, off);
            unsigned ol = __shfl_xor(ml, off);
            bool take = (ov < mv) || (ov == mv && (lane & off));
            mv = take ? ov : mv;
            ml = take ? ol : ml;
        }
        ull bl = __ballot(act && (unsigned)(cur >> 32) == mv);
        int wl = (int)(__ffsll((long long)bl) - 1);
        if (lane == wl) {
            ++ptr;
            cur = (ptr < KSEL) ? lst[ptr] : ~0ull;
        }
        if (lane == 0) {
            float d = sqrtf(__uint_as_float(mv));
            if (it == 0) d0 = d;
            float w = expf((d0 - d) * INV_T);
            sw += w;
            sl += w * __uint_as_float(ml);
        }
    }
    if (lane == 0) out[q] = sl / sw;
}

// ---------------------------------------------------------------------------
extern "C" void kernel_launch(void* const* d_in, const int* in_sizes, int n_in,
                              void* d_out, int out_size, void* d_ws, size_t ws_size,
                              hipStream_t stream) {
    const float* x      = (const float*)d_in[0];   // [256,256]
    const float* sx     = (const float*)d_in[1];   // [16384,256]
    const float* labels = (const float*)d_in[2];   // [16384,1]
    const float* W1     = (const float*)d_in[3];   // [64,256]
    const float* b1     = (const float*)d_in[4];
    const float* W2     = (const float*)d_in[5];   // [64,64]
    const float* b2     = (const float*)d_in[6];
    const float* W3     = (const float*)d_in[7];   // [64,64]
    const float* b3     = (const float*)d_in[8];
    float* out = (float*)d_out;

    float* ws     = (float*)d_ws;
    float* s_emb  = ws;                              // 16384*64
    float* s_norm = s_emb + (size_t)N_SUP * D_E;     // 16384
    float* q_emb  = s_norm + N_SUP;                  // 256*64
    float* q_norm = q_emb + (size_t)NQ * D_E;        // 256
    ull*   cand   = (ull*)(q_norm + NQ);             // 256*32*32 ull = 2 MB

    embed_kernel<<<(N_SUP + NQ) / 64, 256, 0, stream>>>(
        sx, x, W1, b1, W2, b2, W3, b3, s_emb, s_norm, q_emb, q_norm);
    knn_phaseA<<<NQG * NCH, 512, 0, stream>>>(s_emb, s_norm, q_emb, q_norm,
                                              labels, cand);
    knn_phaseB<<<NQ / 4, 256, 0, stream>>>(cand, out);
}